// Round 1
// baseline (2162.386 us; speedup 1.0000x reference)
//
#include <hip/hip_runtime.h>

#define N_FEATS 128

// ---------------------------------------------------------------------------
// deg[d] += 1 per edge
__global__ void deg_kernel(const int* __restrict__ dst, float* __restrict__ deg,
                           int n_edges) {
    int i = blockIdx.x * blockDim.x + threadIdx.x;
    if (i < n_edges) atomicAdd(&deg[dst[i]], 1.0f);
}

// ---------------------------------------------------------------------------
// msg[dst[e]] += h[src[e]]  (128 feats per edge; 32 threads/edge, float4 each)
__global__ void scatter_kernel(const float* __restrict__ h,
                               const int* __restrict__ src,
                               const int* __restrict__ dst,
                               float* __restrict__ msg, int n_edges) {
    int tid = blockIdx.x * blockDim.x + threadIdx.x;
    int e = tid >> 5;
    if (e >= n_edges) return;
    int g = tid & 31;
    int s = src[e], d = dst[e];
    float4 v = reinterpret_cast<const float4*>(h)[s * 32 + g];
    float* o = msg + (size_t)d * N_FEATS + g * 4;
    atomicAdd(o + 0, v.x);
    atomicAdd(o + 1, v.y);
    atomicAdd(o + 2, v.z);
    atomicAdd(o + 3, v.w);
}

// ---------------------------------------------------------------------------
// hout = act( ((msg + hin) * 1/(deg+1)) @ W + b )
// W: [128][OUT] row-major.  Block = 256 threads; each thread: 1 row, 8 cols.
template <int OUT, bool RELU>
__global__ void layer_kernel(const float* __restrict__ msg,
                             const float* __restrict__ hin,
                             const float* __restrict__ deg,
                             const float* __restrict__ W,
                             const float* __restrict__ b,
                             float* __restrict__ hout, int n_nodes) {
    constexpr int CPT  = 8;            // cols per thread
    constexpr int TPR  = OUT / CPT;    // threads per row
    constexpr int ROWS = 256 / TPR;    // rows per block
    __shared__ float Ws[N_FEATS * OUT];
    __shared__ float As[ROWS][N_FEATS + 4];  // +4 pad: distinct banks per row

    int t = threadIdx.x;
    // stage W (coalesced float4)
    {
        const float4* Wg = reinterpret_cast<const float4*>(W);
        float4* Wl = reinterpret_cast<float4*>(Ws);
        for (int i = t; i < N_FEATS * OUT / 4; i += 256) Wl[i] = Wg[i];
    }
    int row0 = blockIdx.x * ROWS;
    // stage A tile: (msg + hin) / (deg + 1)
    for (int i = t; i < ROWS * (N_FEATS / 4); i += 256) {
        int r  = i / (N_FEATS / 4);
        int c4 = i % (N_FEATS / 4);
        int gr = row0 + r;
        float4 a = make_float4(0.f, 0.f, 0.f, 0.f);
        if (gr < n_nodes) {
            float4 m = reinterpret_cast<const float4*>(msg)[gr * 32 + c4];
            float4 x = reinterpret_cast<const float4*>(hin)[gr * 32 + c4];
            float inv = 1.0f / (deg[gr] + 1.0f);
            a.x = (m.x + x.x) * inv;
            a.y = (m.y + x.y) * inv;
            a.z = (m.z + x.z) * inv;
            a.w = (m.w + x.w) * inv;
        }
        *reinterpret_cast<float4*>(&As[r][c4 * 4]) = a;
    }
    __syncthreads();

    int row = t / TPR;
    int c0  = (t % TPR) * CPT;
    int gr  = row0 + row;
    float acc[CPT];
#pragma unroll
    for (int j = 0; j < CPT; j++) acc[j] = b[c0 + j];
    for (int k = 0; k < N_FEATS; k++) {
        float av = As[row][k];
#pragma unroll
        for (int j = 0; j < CPT; j++) acc[j] += av * Ws[k * OUT + c0 + j];
    }
    if (gr < n_nodes) {
#pragma unroll
        for (int j = 0; j < CPT; j++) {
            float v = acc[j];
            if (RELU) v = fmaxf(v, 0.0f);
            hout[(size_t)gr * OUT + c0 + j] = v;
        }
    }
}

// ---------------------------------------------------------------------------
extern "C" void kernel_launch(void* const* d_in, const int* in_sizes, int n_in,
                              void* d_out, int out_size, void* d_ws, size_t ws_size,
                              hipStream_t stream) {
    const float* x   = (const float*)d_in[0];
    const int*   src = (const int*)d_in[1];
    const int*   dst = (const int*)d_in[2];
    const float* W1  = (const float*)d_in[3];
    const float* b1  = (const float*)d_in[4];
    const float* W2  = (const float*)d_in[5];
    const float* b2  = (const float*)d_in[6];
    float* out = (float*)d_out;

    const int n_nodes = in_sizes[0] / N_FEATS;
    const int n_edges = in_sizes[1];

    // workspace layout: deg | msg | h   (≈51.4 MB)
    size_t npad = ((size_t)n_nodes + 127) & ~(size_t)127;
    float* deg = (float*)d_ws;
    float* msg = deg + npad;
    float* h   = msg + npad * N_FEATS;

    // zero deg + msg (contiguous)
    hipMemsetAsync(deg, 0, (npad + npad * N_FEATS) * sizeof(float), stream);

    deg_kernel<<<(n_edges + 255) / 256, 256, 0, stream>>>(dst, deg, n_edges);

    int sc_blocks = (int)(((long long)n_edges * 32 + 255) / 256);
    scatter_kernel<<<sc_blocks, 256, 0, stream>>>(x, src, dst, msg, n_edges);

    layer_kernel<128, true><<<(n_nodes + 15) / 16, 256, 0, stream>>>(
        msg, x, deg, W1, b1, h, n_nodes);

    hipMemsetAsync(msg, 0, npad * N_FEATS * sizeof(float), stream);

    scatter_kernel<<<sc_blocks, 256, 0, stream>>>(h, src, dst, msg, n_edges);

    layer_kernel<64, false><<<(n_nodes + 31) / 32, 256, 0, stream>>>(
        msg, h, deg, W2, b2, out, n_nodes);
}

// Round 2
// 447.054 us; speedup vs baseline: 4.8370x; 4.8370x over previous
//
#include <hip/hip_runtime.h>

#define NF 128

// ---------------------------------------------------------------------------
// cnt[dst[e]] += 1
__global__ void hist_kernel(const int* __restrict__ dst, int* __restrict__ cnt,
                            int n_edges) {
    int i = blockIdx.x * blockDim.x + threadIdx.x;
    if (i < n_edges) atomicAdd(&cnt[dst[i]], 1);
}

// ---------------------------------------------------------------------------
// Single-block scan: rowptr[0]=0; rowptr[i+1]=inclusive_prefix(cnt,i);
// cnt[i] <- exclusive prefix (becomes the fill cursor).
__global__ void scan_kernel(int* __restrict__ cnt, int* __restrict__ rowptr,
                            int n) {
    __shared__ int s[1024];
    __shared__ int carry;
    int t = threadIdx.x;
    if (t == 0) { carry = 0; rowptr[0] = 0; }
    __syncthreads();
    for (int base = 0; base < n; base += 1024) {
        int i = base + t;
        int v = (i < n) ? cnt[i] : 0;
        int acc = v;
        s[t] = acc;
        __syncthreads();
        for (int off = 1; off < 1024; off <<= 1) {
            int add = (t >= off) ? s[t - off] : 0;
            __syncthreads();
            acc += add;
            s[t] = acc;
            __syncthreads();
        }
        int run = carry;
        if (i < n) {
            rowptr[i + 1] = run + acc;   // inclusive prefix
            cnt[i] = run + acc - v;      // exclusive prefix -> cursor
        }
        __syncthreads();
        if (t == 1023) carry = run + acc;
        __syncthreads();
    }
}

// ---------------------------------------------------------------------------
// edge_src[cursor[dst[e]]++] = src[e]
__global__ void fill_kernel(const int* __restrict__ src,
                            const int* __restrict__ dst,
                            int* __restrict__ cursor,
                            int* __restrict__ edge_src, int n_edges) {
    int i = blockIdx.x * blockDim.x + threadIdx.x;
    if (i < n_edges) {
        int slot = atomicAdd(&cursor[dst[i]], 1);
        edge_src[slot] = src[i];
    }
}

// ---------------------------------------------------------------------------
// Fused: gather neighbor rows (CSR) + normalize + GEMM + bias (+ReLU).
// hout[i] = act( ((sum_nbrs hin[j] + hin[i]) / (deg+1)) @ W + b )
template <int OUT, bool RELU>
__global__ __launch_bounds__(256) void sage_layer_kernel(
    const float* __restrict__ hin, const int* __restrict__ rowptr,
    const int* __restrict__ edge_src, const float* __restrict__ W,
    const float* __restrict__ b, float* __restrict__ hout, int n_nodes) {
    constexpr int CPT  = 8;            // cols per thread
    constexpr int TPR  = OUT / CPT;    // threads per row
    constexpr int ROWS = 256 / TPR;    // rows per block
    __shared__ float Ws[NF * OUT];
    __shared__ float As[ROWS][NF + 4];

    int t = threadIdx.x;
    // stage W (coalesced float4)
    {
        const float4* Wg = reinterpret_cast<const float4*>(W);
        float4* Wl = reinterpret_cast<float4*>(Ws);
        for (int i = t; i < NF * OUT / 4; i += 256) Wl[i] = Wg[i];
    }

    int row0 = blockIdx.x * ROWS;
    // gather phase: 8 node-slots x 32 lanes (float4 per lane)
    int nslot = t >> 5;
    int g     = t & 31;
    for (int r = nslot; r < ROWS; r += 8) {
        int gr = row0 + r;
        float4 acc = make_float4(0.f, 0.f, 0.f, 0.f);
        if (gr < n_nodes) {
            int e0 = rowptr[gr], e1 = rowptr[gr + 1];
            acc = reinterpret_cast<const float4*>(hin)[(size_t)gr * 32 + g];
            for (int e = e0; e < e1; ++e) {
                int s = edge_src[e];
                float4 v = reinterpret_cast<const float4*>(hin)[(size_t)s * 32 + g];
                acc.x += v.x; acc.y += v.y; acc.z += v.z; acc.w += v.w;
            }
            float inv = 1.0f / (float)(e1 - e0 + 1);
            acc.x *= inv; acc.y *= inv; acc.z *= inv; acc.w *= inv;
        }
        *reinterpret_cast<float4*>(&As[r][g * 4]) = acc;
    }
    __syncthreads();

    // GEMM phase
    int row = t / TPR;
    int c0  = (t % TPR) * CPT;
    int gr  = row0 + row;
    float accum[CPT];
#pragma unroll
    for (int j = 0; j < CPT; j++) accum[j] = b[c0 + j];
    for (int k = 0; k < NF; k++) {
        float av = As[row][k];
#pragma unroll
        for (int j = 0; j < CPT; j++) accum[j] += av * Ws[k * OUT + c0 + j];
    }
    if (gr < n_nodes) {
#pragma unroll
        for (int j = 0; j < CPT; j++) {
            float v = accum[j];
            if (RELU) v = fmaxf(v, 0.0f);
            hout[(size_t)gr * OUT + c0 + j] = v;
        }
    }
}

// ---------------------------------------------------------------------------
extern "C" void kernel_launch(void* const* d_in, const int* in_sizes, int n_in,
                              void* d_out, int out_size, void* d_ws, size_t ws_size,
                              hipStream_t stream) {
    const float* x   = (const float*)d_in[0];
    const int*   src = (const int*)d_in[1];
    const int*   dst = (const int*)d_in[2];
    const float* W1  = (const float*)d_in[3];
    const float* b1  = (const float*)d_in[4];
    const float* W2  = (const float*)d_in[5];
    const float* b2  = (const float*)d_in[6];
    float* out = (float*)d_out;

    const int n_nodes = in_sizes[0] / NF;   // 50000
    const int n_edges = in_sizes[1];        // 600000

    // workspace layout (ints then floats, 16B-aligned h):
    //   rowptr[50004] | cnt[n] | edge_src[E] | h[n*128]
    int* rowptr   = (int*)d_ws;
    int* cnt      = rowptr + 50004;
    int* edge_src = cnt + n_nodes;
    float* h      = (float*)(edge_src + n_edges);

    hipMemsetAsync(cnt, 0, (size_t)n_nodes * sizeof(int), stream);

    int eb = (n_edges + 255) / 256;
    hist_kernel<<<eb, 256, 0, stream>>>(dst, cnt, n_edges);
    scan_kernel<<<1, 1024, 0, stream>>>(cnt, rowptr, n_nodes);
    fill_kernel<<<eb, 256, 0, stream>>>(src, dst, cnt, edge_src, n_edges);

    sage_layer_kernel<128, true><<<(n_nodes + 15) / 16, 256, 0, stream>>>(
        x, rowptr, edge_src, W1, b1, h, n_nodes);
    sage_layer_kernel<64, false><<<(n_nodes + 31) / 32, 256, 0, stream>>>(
        h, rowptr, edge_src, W2, b2, out, n_nodes);
}

// Round 3
// 343.696 us; speedup vs baseline: 6.2916x; 1.3007x over previous
//
#include <hip/hip_runtime.h>

#define NF 128

// ---------------------------------------------------------------------------
// cnt[dst[e]] += 1
__global__ void hist_kernel(const int* __restrict__ dst, int* __restrict__ cnt,
                            int n_edges) {
    int i = blockIdx.x * blockDim.x + threadIdx.x;
    if (i < n_edges) atomicAdd(&cnt[dst[i]], 1);
}

// ---------------------------------------------------------------------------
// Single-block scan, thread-owns-chunk. After: rowptr[i+1] = incl prefix,
// cnt[i] = excl prefix (fill cursor), rowptr[0] = 0.
__global__ __launch_bounds__(1024) void scan_kernel(int* __restrict__ cnt,
                                                    int* __restrict__ rowptr,
                                                    int n) {
    __shared__ int totals[1024];
    int t = threadIdx.x;
    int chunk = (n + 1023) >> 10;
    int lo = t * chunk;
    int hi = min(lo + chunk, n);
    int sum = 0;
    for (int i = lo; i < hi; ++i) sum += cnt[i];
    totals[t] = sum;
    __syncthreads();
    for (int off = 1; off < 1024; off <<= 1) {
        int v = (t >= off) ? totals[t - off] : 0;
        __syncthreads();
        totals[t] += v;
        __syncthreads();
    }
    int run = (t > 0) ? totals[t - 1] : 0;
    if (t == 0) rowptr[0] = 0;
    for (int i = lo; i < hi; ++i) {
        int v = cnt[i];
        cnt[i] = run;          // cursor = exclusive prefix
        run += v;
        rowptr[i + 1] = run;   // inclusive prefix
    }
}

// ---------------------------------------------------------------------------
// edge_src[cursor[dst[e]]++] = src[e]
__global__ void fill_kernel(const int* __restrict__ src,
                            const int* __restrict__ dst,
                            int* __restrict__ cursor,
                            int* __restrict__ edge_src, int n_edges) {
    int i = blockIdx.x * blockDim.x + threadIdx.x;
    if (i < n_edges) {
        int slot = atomicAdd(&cursor[dst[i]], 1);
        edge_src[slot] = src[i];
    }
}

// ---------------------------------------------------------------------------
// hn[i] = (sum_nbrs hin[j] + hin[i]) / (deg+1).  32 lanes per node, float4
// per lane. Edge srcs prefetched 32-wide + shfl broadcast; x4 unroll for MLP.
__global__ __launch_bounds__(256) void aggregate_kernel(
    const float* __restrict__ hin, const int* __restrict__ rowptr,
    const int* __restrict__ edge_src, float* __restrict__ hn, int n_nodes) {
    int t = threadIdx.x;
    int g = t & 31;
    int node = blockIdx.x * 8 + (t >> 5);
    if (node >= n_nodes) return;
    const float4* h4 = reinterpret_cast<const float4*>(hin);
    int e0 = rowptr[node], e1 = rowptr[node + 1];
    float4 a0 = h4[(size_t)node * 32 + g];  // self term
    float4 a1 = make_float4(0.f, 0.f, 0.f, 0.f);
    float4 a2 = make_float4(0.f, 0.f, 0.f, 0.f);
    float4 a3 = make_float4(0.f, 0.f, 0.f, 0.f);
    for (int base = e0; base < e1; base += 32) {
        int m = min(32, e1 - base);
        int sg = (base + g < e1) ? edge_src[base + g] : 0;
        int j = 0;
        for (; j + 4 <= m; j += 4) {
            int s0 = __shfl(sg, j, 32);
            int s1 = __shfl(sg, j + 1, 32);
            int s2 = __shfl(sg, j + 2, 32);
            int s3 = __shfl(sg, j + 3, 32);
            float4 v0 = h4[(size_t)s0 * 32 + g];
            float4 v1 = h4[(size_t)s1 * 32 + g];
            float4 v2 = h4[(size_t)s2 * 32 + g];
            float4 v3 = h4[(size_t)s3 * 32 + g];
            a0.x += v0.x; a0.y += v0.y; a0.z += v0.z; a0.w += v0.w;
            a1.x += v1.x; a1.y += v1.y; a1.z += v1.z; a1.w += v1.w;
            a2.x += v2.x; a2.y += v2.y; a2.z += v2.z; a2.w += v2.w;
            a3.x += v3.x; a3.y += v3.y; a3.z += v3.z; a3.w += v3.w;
        }
        for (; j < m; ++j) {
            int s = __shfl(sg, j, 32);
            float4 v = h4[(size_t)s * 32 + g];
            a0.x += v.x; a0.y += v.y; a0.z += v.z; a0.w += v.w;
        }
    }
    float inv = 1.0f / (float)(e1 - e0 + 1);
    float4 r;
    r.x = (a0.x + a1.x + a2.x + a3.x) * inv;
    r.y = (a0.y + a1.y + a2.y + a3.y) * inv;
    r.z = (a0.z + a1.z + a2.z + a3.z) * inv;
    r.w = (a0.w + a1.w + a2.w + a3.w) * inv;
    reinterpret_cast<float4*>(hn)[(size_t)node * 32 + g] = r;
}

// ---------------------------------------------------------------------------
// out[:, c_base:c_base+64] = act(A @ W[:, c_base:c_base+64] + b)
// A: [n][128], W: [128][OUTW]. Block: 16 rows x 64 cols, 256 threads,
// each thread one float4 of outputs.
template <int OUTW, bool RELU>
__global__ __launch_bounds__(256) void gemm_kernel(
    const float* __restrict__ A, const float* __restrict__ W,
    const float* __restrict__ bias, float* __restrict__ out, int n_nodes) {
    __shared__ float Ws[NF][64];       // 32 KB
    __shared__ float As[16][NF + 4];   // pad 4: conflict-free row-broadcast

    int t = threadIdx.x;
    int c_base = blockIdx.y * 64;
    const float4* Wg = reinterpret_cast<const float4*>(W);
    for (int i = t; i < NF * 16; i += 256) {
        int k = i >> 4, c4 = i & 15;
        *reinterpret_cast<float4*>(&Ws[k][c4 * 4]) =
            Wg[k * (OUTW / 4) + (c_base / 4) + c4];
    }
    int row0 = blockIdx.x * 16;
    const float4* Ag = reinterpret_cast<const float4*>(A);
    for (int i = t; i < 16 * 32; i += 256) {
        int r = i >> 5, c4 = i & 31;
        int gr = row0 + r;
        float4 v = make_float4(0.f, 0.f, 0.f, 0.f);
        if (gr < n_nodes) v = Ag[(size_t)gr * 32 + c4];
        *reinterpret_cast<float4*>(&As[r][c4 * 4]) = v;
    }
    __syncthreads();

    int row = t >> 4;
    int c4 = t & 15;
    int gr = row0 + row;
    float4 acc;
    acc.x = bias[c_base + c4 * 4 + 0];
    acc.y = bias[c_base + c4 * 4 + 1];
    acc.z = bias[c_base + c4 * 4 + 2];
    acc.w = bias[c_base + c4 * 4 + 3];
#pragma unroll 4
    for (int k = 0; k < NF; ++k) {
        float a = As[row][k];
        float4 w = *reinterpret_cast<const float4*>(&Ws[k][c4 * 4]);
        acc.x += a * w.x;
        acc.y += a * w.y;
        acc.z += a * w.z;
        acc.w += a * w.w;
    }
    if (gr < n_nodes) {
        if (RELU) {
            acc.x = fmaxf(acc.x, 0.f);
            acc.y = fmaxf(acc.y, 0.f);
            acc.z = fmaxf(acc.z, 0.f);
            acc.w = fmaxf(acc.w, 0.f);
        }
        reinterpret_cast<float4*>(out)[((size_t)gr * OUTW + c_base) / 4 + c4] = acc;
    }
}

// ---------------------------------------------------------------------------
extern "C" void kernel_launch(void* const* d_in, const int* in_sizes, int n_in,
                              void* d_out, int out_size, void* d_ws, size_t ws_size,
                              hipStream_t stream) {
    const float* x   = (const float*)d_in[0];
    const int*   src = (const int*)d_in[1];
    const int*   dst = (const int*)d_in[2];
    const float* W1  = (const float*)d_in[3];
    const float* b1  = (const float*)d_in[4];
    const float* W2  = (const float*)d_in[5];
    const float* b2  = (const float*)d_in[6];
    float* out = (float*)d_out;

    const int n_nodes = in_sizes[0] / NF;   // 50000
    const int n_edges = in_sizes[1];        // 600000

    // workspace: rowptr[n+4] | cnt[n] | edge_src[E] | hn[n*128] | h[n*128]
    int* rowptr   = (int*)d_ws;
    int* cnt      = rowptr + (n_nodes + 4);
    int* edge_src = cnt + n_nodes;
    size_t int_words = (size_t)(n_nodes + 4) + n_nodes + n_edges;
    int_words = (int_words + 31) & ~(size_t)31;  // 128B align
    float* hn = (float*)d_ws + int_words;
    float* h  = hn + (size_t)n_nodes * NF;

    hipMemsetAsync(cnt, 0, (size_t)n_nodes * sizeof(int), stream);

    int eb = (n_edges + 255) / 256;
    hist_kernel<<<eb, 256, 0, stream>>>(dst, cnt, n_edges);
    scan_kernel<<<1, 1024, 0, stream>>>(cnt, rowptr, n_nodes);
    fill_kernel<<<eb, 256, 0, stream>>>(src, dst, cnt, edge_src, n_edges);

    int ab = (n_nodes + 7) / 8;
    int gb = (n_nodes + 15) / 16;

    aggregate_kernel<<<ab, 256, 0, stream>>>(x, rowptr, edge_src, hn, n_nodes);
    gemm_kernel<128, true><<<dim3(gb, 2), 256, 0, stream>>>(hn, W1, b1, h, n_nodes);
    aggregate_kernel<<<ab, 256, 0, stream>>>(h, rowptr, edge_src, hn, n_nodes);
    gemm_kernel<64, false><<<dim3(gb, 1), 256, 0, stream>>>(hn, W2, b2, out, n_nodes);
}

// Round 4
// 241.441 us; speedup vs baseline: 8.9562x; 1.4235x over previous
//
#include <hip/hip_runtime.h>

#define NF 128

// ---------------------------------------------------------------------------
// cnt[dst[e]] += 1
__global__ void hist_kernel(const int* __restrict__ dst, int* __restrict__ cnt,
                            int n_edges) {
    int i = blockIdx.x * blockDim.x + threadIdx.x;
    if (i < n_edges) atomicAdd(&cnt[dst[i]], 1);
}

// ---------------------------------------------------------------------------
// partials[b] = sum(cnt[b*256 : (b+1)*256])
__global__ __launch_bounds__(256) void reduce_kernel(const int* __restrict__ cnt,
                                                     int* __restrict__ partials,
                                                     int n) {
    __shared__ int s[256];
    int t = threadIdx.x;
    int i = blockIdx.x * 256 + t;
    s[t] = (i < n) ? cnt[i] : 0;
    __syncthreads();
    for (int off = 128; off > 0; off >>= 1) {
        if (t < off) s[t] += s[t + off];
        __syncthreads();
    }
    if (t == 0) partials[blockIdx.x] = s[0];
}

// ---------------------------------------------------------------------------
// partials[b] <- exclusive prefix sum of partials (single small block)
__global__ __launch_bounds__(256) void scan_partials_kernel(int* __restrict__ partials,
                                                            int nb) {
    __shared__ int s[256];
    int t = threadIdx.x;
    int carry = 0;
    for (int base = 0; base < nb; base += 256) {
        int v = (base + t < nb) ? partials[base + t] : 0;
        s[t] = v;
        __syncthreads();
        for (int off = 1; off < 256; off <<= 1) {
            int a = (t >= off) ? s[t - off] : 0;
            __syncthreads();
            s[t] += a;
            __syncthreads();
        }
        if (base + t < nb) partials[base + t] = carry + s[t] - v;  // exclusive
        int total = s[255];
        __syncthreads();
        carry += total;
    }
}

// ---------------------------------------------------------------------------
// Block-local scan + partial offset. rowptr[i+1] = incl prefix; cnt[i] =
// excl prefix (fill cursor); rowptr[0] = 0.
__global__ __launch_bounds__(256) void scan_apply_kernel(int* __restrict__ cnt,
                                                         int* __restrict__ rowptr,
                                                         const int* __restrict__ partials,
                                                         int n) {
    __shared__ int s[256];
    int t = threadIdx.x;
    int i = blockIdx.x * 256 + t;
    int v = (i < n) ? cnt[i] : 0;
    s[t] = v;
    __syncthreads();
    for (int off = 1; off < 256; off <<= 1) {
        int a = (t >= off) ? s[t - off] : 0;
        __syncthreads();
        s[t] += a;
        __syncthreads();
    }
    int off0 = partials[blockIdx.x];
    if (i < n) {
        rowptr[i + 1] = off0 + s[t];
        cnt[i] = off0 + s[t] - v;
    }
    if (blockIdx.x == 0 && t == 0) rowptr[0] = 0;
}

// ---------------------------------------------------------------------------
// edge_src[cursor[dst[e]]++] = src[e]
__global__ void fill_kernel(const int* __restrict__ src,
                            const int* __restrict__ dst,
                            int* __restrict__ cursor,
                            int* __restrict__ edge_src, int n_edges) {
    int i = blockIdx.x * blockDim.x + threadIdx.x;
    if (i < n_edges) {
        int slot = atomicAdd(&cursor[dst[i]], 1);
        edge_src[slot] = src[i];
    }
}

// ---------------------------------------------------------------------------
// hn[i] = (sum_nbrs hin[j] + hin[i]) / (deg+1).  32 lanes per node, float4
// per lane. Edge srcs prefetched 32-wide + shfl broadcast; x4 unroll for MLP.
__global__ __launch_bounds__(256) void aggregate_kernel(
    const float* __restrict__ hin, const int* __restrict__ rowptr,
    const int* __restrict__ edge_src, float* __restrict__ hn, int n_nodes) {
    int t = threadIdx.x;
    int g = t & 31;
    int node = blockIdx.x * 8 + (t >> 5);
    if (node >= n_nodes) return;
    const float4* h4 = reinterpret_cast<const float4*>(hin);
    int e0 = rowptr[node], e1 = rowptr[node + 1];
    float4 a0 = h4[(size_t)node * 32 + g];  // self term
    float4 a1 = make_float4(0.f, 0.f, 0.f, 0.f);
    float4 a2 = make_float4(0.f, 0.f, 0.f, 0.f);
    float4 a3 = make_float4(0.f, 0.f, 0.f, 0.f);
    for (int base = e0; base < e1; base += 32) {
        int m = min(32, e1 - base);
        int sg = (base + g < e1) ? edge_src[base + g] : 0;
        int j = 0;
        for (; j + 4 <= m; j += 4) {
            int s0 = __shfl(sg, j, 32);
            int s1 = __shfl(sg, j + 1, 32);
            int s2 = __shfl(sg, j + 2, 32);
            int s3 = __shfl(sg, j + 3, 32);
            float4 v0 = h4[(size_t)s0 * 32 + g];
            float4 v1 = h4[(size_t)s1 * 32 + g];
            float4 v2 = h4[(size_t)s2 * 32 + g];
            float4 v3 = h4[(size_t)s3 * 32 + g];
            a0.x += v0.x; a0.y += v0.y; a0.z += v0.z; a0.w += v0.w;
            a1.x += v1.x; a1.y += v1.y; a1.z += v1.z; a1.w += v1.w;
            a2.x += v2.x; a2.y += v2.y; a2.z += v2.z; a2.w += v2.w;
            a3.x += v3.x; a3.y += v3.y; a3.z += v3.z; a3.w += v3.w;
        }
        for (; j < m; ++j) {
            int s = __shfl(sg, j, 32);
            float4 v = h4[(size_t)s * 32 + g];
            a0.x += v.x; a0.y += v.y; a0.z += v.z; a0.w += v.w;
        }
    }
    float inv = 1.0f / (float)(e1 - e0 + 1);
    float4 r;
    r.x = (a0.x + a1.x + a2.x + a3.x) * inv;
    r.y = (a0.y + a1.y + a2.y + a3.y) * inv;
    r.z = (a0.z + a1.z + a2.z + a3.z) * inv;
    r.w = (a0.w + a1.w + a2.w + a3.w) * inv;
    reinterpret_cast<float4*>(hn)[(size_t)node * 32 + g] = r;
}

// ---------------------------------------------------------------------------
// out[:, c_base:c_base+64] = act(A @ W[:, c_base:c_base+64] + b)
// A: [n][128], W: [128][OUTW]. Block: 16 rows x 64 cols, 256 threads,
// each thread one float4 of outputs.
template <int OUTW, bool RELU>
__global__ __launch_bounds__(256) void gemm_kernel(
    const float* __restrict__ A, const float* __restrict__ W,
    const float* __restrict__ bias, float* __restrict__ out, int n_nodes) {
    __shared__ float Ws[NF][64];       // 32 KB
    __shared__ float As[16][NF + 4];   // pad 4: conflict-free row-broadcast

    int t = threadIdx.x;
    int c_base = blockIdx.y * 64;
    const float4* Wg = reinterpret_cast<const float4*>(W);
    for (int i = t; i < NF * 16; i += 256) {
        int k = i >> 4, c4 = i & 15;
        *reinterpret_cast<float4*>(&Ws[k][c4 * 4]) =
            Wg[k * (OUTW / 4) + (c_base / 4) + c4];
    }
    int row0 = blockIdx.x * 16;
    const float4* Ag = reinterpret_cast<const float4*>(A);
    for (int i = t; i < 16 * 32; i += 256) {
        int r = i >> 5, c4 = i & 31;
        int gr = row0 + r;
        float4 v = make_float4(0.f, 0.f, 0.f, 0.f);
        if (gr < n_nodes) v = Ag[(size_t)gr * 32 + c4];
        *reinterpret_cast<float4*>(&As[r][c4 * 4]) = v;
    }
    __syncthreads();

    int row = t >> 4;
    int c4 = t & 15;
    int gr = row0 + row;
    float4 acc;
    acc.x = bias[c_base + c4 * 4 + 0];
    acc.y = bias[c_base + c4 * 4 + 1];
    acc.z = bias[c_base + c4 * 4 + 2];
    acc.w = bias[c_base + c4 * 4 + 3];
#pragma unroll 4
    for (int k = 0; k < NF; ++k) {
        float a = As[row][k];
        float4 w = *reinterpret_cast<const float4*>(&Ws[k][c4 * 4]);
        acc.x += a * w.x;
        acc.y += a * w.y;
        acc.z += a * w.z;
        acc.w += a * w.w;
    }
    if (gr < n_nodes) {
        if (RELU) {
            acc.x = fmaxf(acc.x, 0.f);
            acc.y = fmaxf(acc.y, 0.f);
            acc.z = fmaxf(acc.z, 0.f);
            acc.w = fmaxf(acc.w, 0.f);
        }
        reinterpret_cast<float4*>(out)[((size_t)gr * OUTW + c_base) / 4 + c4] = acc;
    }
}

// ---------------------------------------------------------------------------
extern "C" void kernel_launch(void* const* d_in, const int* in_sizes, int n_in,
                              void* d_out, int out_size, void* d_ws, size_t ws_size,
                              hipStream_t stream) {
    const float* x   = (const float*)d_in[0];
    const int*   src = (const int*)d_in[1];
    const int*   dst = (const int*)d_in[2];
    const float* W1  = (const float*)d_in[3];
    const float* b1  = (const float*)d_in[4];
    const float* W2  = (const float*)d_in[5];
    const float* b2  = (const float*)d_in[6];
    float* out = (float*)d_out;

    const int n_nodes = in_sizes[0] / NF;   // 50000
    const int n_edges = in_sizes[1];        // 600000
    const int nb = (n_nodes + 255) / 256;   // scan blocks

    // workspace: rowptr[n+4] | cnt[n] | edge_src[E] | partials[nb] | hn | h
    int* rowptr   = (int*)d_ws;
    int* cnt      = rowptr + (n_nodes + 4);
    int* edge_src = cnt + n_nodes;
    int* partials = edge_src + n_edges;
    size_t int_words = (size_t)(n_nodes + 4) + n_nodes + n_edges + nb;
    int_words = (int_words + 31) & ~(size_t)31;  // 128B align
    float* hn = (float*)d_ws + int_words;
    float* h  = hn + (size_t)n_nodes * NF;

    hipMemsetAsync(cnt, 0, (size_t)n_nodes * sizeof(int), stream);

    int eb = (n_edges + 255) / 256;
    hist_kernel<<<eb, 256, 0, stream>>>(dst, cnt, n_edges);
    reduce_kernel<<<nb, 256, 0, stream>>>(cnt, partials, n_nodes);
    scan_partials_kernel<<<1, 256, 0, stream>>>(partials, nb);
    scan_apply_kernel<<<nb, 256, 0, stream>>>(cnt, rowptr, partials, n_nodes);
    fill_kernel<<<eb, 256, 0, stream>>>(src, dst, cnt, edge_src, n_edges);

    int ab = (n_nodes + 7) / 8;
    int gb = (n_nodes + 15) / 16;

    aggregate_kernel<<<ab, 256, 0, stream>>>(x, rowptr, edge_src, hn, n_nodes);
    gemm_kernel<128, true><<<dim3(gb, 2), 256, 0, stream>>>(hn, W1, b1, h, n_nodes);
    aggregate_kernel<<<ab, 256, 0, stream>>>(h, rowptr, edge_src, hn, n_nodes);
    gemm_kernel<64, false><<<dim3(gb, 1), 256, 0, stream>>>(hn, W2, b2, out, n_nodes);
}

// Round 5
// 191.760 us; speedup vs baseline: 11.2765x; 1.2591x over previous
//
#include <hip/hip_runtime.h>

#define NF 128

typedef __attribute__((ext_vector_type(8))) short short8;
typedef __attribute__((ext_vector_type(4))) float f32x4;

__device__ inline ushort f2bf(float f) {
    uint u = __float_as_uint(f);
    return (ushort)((u + 0x7FFFu + ((u >> 16) & 1u)) >> 16);  // RNE
}

// ---------------------------------------------------------------------------
// cnt[dst[e]] += 1
__global__ void hist_kernel(const int* __restrict__ dst, int* __restrict__ cnt,
                            int n_edges) {
    int i = blockIdx.x * blockDim.x + threadIdx.x;
    if (i < n_edges) atomicAdd(&cnt[dst[i]], 1);
}

// ---------------------------------------------------------------------------
__global__ __launch_bounds__(256) void reduce_kernel(const int* __restrict__ cnt,
                                                     int* __restrict__ partials,
                                                     int n) {
    __shared__ int s[256];
    int t = threadIdx.x;
    int i = blockIdx.x * 256 + t;
    s[t] = (i < n) ? cnt[i] : 0;
    __syncthreads();
    for (int off = 128; off > 0; off >>= 1) {
        if (t < off) s[t] += s[t + off];
        __syncthreads();
    }
    if (t == 0) partials[blockIdx.x] = s[0];
}

// ---------------------------------------------------------------------------
__global__ __launch_bounds__(256) void scan_partials_kernel(int* __restrict__ partials,
                                                            int nb) {
    __shared__ int s[256];
    int t = threadIdx.x;
    int carry = 0;
    for (int base = 0; base < nb; base += 256) {
        int v = (base + t < nb) ? partials[base + t] : 0;
        s[t] = v;
        __syncthreads();
        for (int off = 1; off < 256; off <<= 1) {
            int a = (t >= off) ? s[t - off] : 0;
            __syncthreads();
            s[t] += a;
            __syncthreads();
        }
        if (base + t < nb) partials[base + t] = carry + s[t] - v;  // exclusive
        int total = s[255];
        __syncthreads();
        carry += total;
    }
}

// ---------------------------------------------------------------------------
__global__ __launch_bounds__(256) void scan_apply_kernel(int* __restrict__ cnt,
                                                         int* __restrict__ rowptr,
                                                         const int* __restrict__ partials,
                                                         int n) {
    __shared__ int s[256];
    int t = threadIdx.x;
    int i = blockIdx.x * 256 + t;
    int v = (i < n) ? cnt[i] : 0;
    s[t] = v;
    __syncthreads();
    for (int off = 1; off < 256; off <<= 1) {
        int a = (t >= off) ? s[t - off] : 0;
        __syncthreads();
        s[t] += a;
        __syncthreads();
    }
    int off0 = partials[blockIdx.x];
    if (i < n) {
        rowptr[i + 1] = off0 + s[t];
        cnt[i] = off0 + s[t] - v;
    }
    if (blockIdx.x == 0 && t == 0) rowptr[0] = 0;
}

// ---------------------------------------------------------------------------
__global__ void fill_kernel(const int* __restrict__ src,
                            const int* __restrict__ dst,
                            int* __restrict__ cursor,
                            int* __restrict__ edge_src, int n_edges) {
    int i = blockIdx.x * blockDim.x + threadIdx.x;
    if (i < n_edges) {
        int slot = atomicAdd(&cursor[dst[i]], 1);
        edge_src[slot] = src[i];
    }
}

// ---------------------------------------------------------------------------
// W1t[n][k] = bf16(W1[k][n]); W2t[n][k] = bf16(W2[k][n])
__global__ __launch_bounds__(256) void prep_w_kernel(const float* __restrict__ W1,
                                                     const float* __restrict__ W2,
                                                     ushort* __restrict__ W1t,
                                                     ushort* __restrict__ W2t) {
    int t = blockIdx.x * 256 + threadIdx.x;
    if (t < 128 * 128) {
        int k = t >> 7, n = t & 127;
        W1t[n * NF + k] = f2bf(W1[t]);
    }
    if (t < 64 * 128) {
        int k = t >> 6, n = t & 63;
        W2t[n * NF + k] = f2bf(W2[k * 64 + n]);
    }
}

// ---------------------------------------------------------------------------
// hn[i] = bf16( (sum_nbrs hin[j] + hin[i]) / (deg+1) ).  32 lanes/node.
__global__ __launch_bounds__(256) void aggregate_kernel(
    const float* __restrict__ hin, const int* __restrict__ rowptr,
    const int* __restrict__ edge_src, ushort* __restrict__ hn, int n_nodes) {
    int t = threadIdx.x;
    int g = t & 31;
    int node = blockIdx.x * 8 + (t >> 5);
    if (node >= n_nodes) return;
    const float4* h4 = reinterpret_cast<const float4*>(hin);
    int e0 = rowptr[node], e1 = rowptr[node + 1];
    float4 a0 = h4[(size_t)node * 32 + g];  // self term
    float4 a1 = make_float4(0.f, 0.f, 0.f, 0.f);
    float4 a2 = make_float4(0.f, 0.f, 0.f, 0.f);
    float4 a3 = make_float4(0.f, 0.f, 0.f, 0.f);
    for (int base = e0; base < e1; base += 32) {
        int m = min(32, e1 - base);
        int sg = (base + g < e1) ? edge_src[base + g] : 0;
        int j = 0;
        for (; j + 4 <= m; j += 4) {
            int s0 = __shfl(sg, j, 32);
            int s1 = __shfl(sg, j + 1, 32);
            int s2 = __shfl(sg, j + 2, 32);
            int s3 = __shfl(sg, j + 3, 32);
            float4 v0 = h4[(size_t)s0 * 32 + g];
            float4 v1 = h4[(size_t)s1 * 32 + g];
            float4 v2 = h4[(size_t)s2 * 32 + g];
            float4 v3 = h4[(size_t)s3 * 32 + g];
            a0.x += v0.x; a0.y += v0.y; a0.z += v0.z; a0.w += v0.w;
            a1.x += v1.x; a1.y += v1.y; a1.z += v1.z; a1.w += v1.w;
            a2.x += v2.x; a2.y += v2.y; a2.z += v2.z; a2.w += v2.w;
            a3.x += v3.x; a3.y += v3.y; a3.z += v3.z; a3.w += v3.w;
        }
        for (; j < m; ++j) {
            int s = __shfl(sg, j, 32);
            float4 v = h4[(size_t)s * 32 + g];
            a0.x += v.x; a0.y += v.y; a0.z += v.z; a0.w += v.w;
        }
    }
    float inv = 1.0f / (float)(e1 - e0 + 1);
    ushort4 o;
    o.x = f2bf((a0.x + a1.x + a2.x + a3.x) * inv);
    o.y = f2bf((a0.y + a1.y + a2.y + a3.y) * inv);
    o.z = f2bf((a0.z + a1.z + a2.z + a3.z) * inv);
    o.w = f2bf((a0.w + a1.w + a2.w + a3.w) * inv);
    reinterpret_cast<ushort4*>(hn)[(size_t)node * 32 + g] = o;
}

// ---------------------------------------------------------------------------
// out = act( A_bf16 @ W + b ), via mfma_f32_16x16x32_bf16.
// A: [n][128] bf16 row-major. Wt: [OUTW][128] bf16 (n-major, k-contiguous).
// Block: 256 thr = 4 waves; BM=64 (16 rows/wave); full OUTW in LDS.
// Fragment layout (K=32 shapes): m/n = lane&15, k = 8*(lane>>4)+i.
// C/D: col = lane&15, row = 4*(lane>>4)+reg  [verified mapping].
template <int OUTW, bool RELU>
__global__ __launch_bounds__(256) void gemm_mfma_kernel(
    const ushort* __restrict__ A, const ushort* __restrict__ Wt,
    const float* __restrict__ bias, float* __restrict__ out, int n_nodes) {
    constexpr int NT = OUTW / 16;
    __shared__ ushort As[64][136];     // pad->272B stride: 16B-aligned rows
    __shared__ ushort Ws[OUTW][136];

    int t = threadIdx.x;
    int row0 = blockIdx.x * 64;
    for (int i = t; i < 64 * 16; i += 256) {       // stage A (bf16x8)
        int r = i >> 4, c = i & 15;
        int gr = row0 + r;
        short8 v = {};
        if (gr < n_nodes)
            v = *reinterpret_cast<const short8*>(&A[(size_t)gr * NF + c * 8]);
        *reinterpret_cast<short8*>(&As[r][c * 8]) = v;
    }
    for (int i = t; i < OUTW * 16; i += 256) {     // stage Wt
        int r = i >> 4, c = i & 15;
        *reinterpret_cast<short8*>(&Ws[r][c * 8]) =
            *reinterpret_cast<const short8*>(&Wt[r * NF + c * 8]);
    }
    __syncthreads();

    int w = t >> 6;
    int l = t & 63;
    int m16 = l & 15;
    int g = l >> 4;
    int m0 = w * 16;

    f32x4 acc[NT];
#pragma unroll
    for (int nt = 0; nt < NT; nt++) acc[nt] = {0.f, 0.f, 0.f, 0.f};

#pragma unroll
    for (int kk = 0; kk < 4; kk++) {
        int k0 = kk * 32 + g * 8;
        short8 a = *reinterpret_cast<const short8*>(&As[m0 + m16][k0]);
#pragma unroll
        for (int nt = 0; nt < NT; nt++) {
            short8 b = *reinterpret_cast<const short8*>(&Ws[nt * 16 + m16][k0]);
            acc[nt] = __builtin_amdgcn_mfma_f32_16x16x32_bf16(a, b, acc[nt], 0, 0, 0);
        }
    }

#pragma unroll
    for (int nt = 0; nt < NT; nt++) {
        int col = nt * 16 + m16;
        float bv = bias[col];
#pragma unroll
        for (int i = 0; i < 4; i++) {
            int gr = row0 + m0 + g * 4 + i;
            if (gr < n_nodes) {
                float v = acc[nt][i] + bv;
                if (RELU) v = fmaxf(v, 0.f);
                out[(size_t)gr * OUTW + col] = v;
            }
        }
    }
}

// ---------------------------------------------------------------------------
extern "C" void kernel_launch(void* const* d_in, const int* in_sizes, int n_in,
                              void* d_out, int out_size, void* d_ws, size_t ws_size,
                              hipStream_t stream) {
    const float* x   = (const float*)d_in[0];
    const int*   src = (const int*)d_in[1];
    const int*   dst = (const int*)d_in[2];
    const float* W1  = (const float*)d_in[3];
    const float* b1  = (const float*)d_in[4];
    const float* W2  = (const float*)d_in[5];
    const float* b2  = (const float*)d_in[6];
    float* out = (float*)d_out;

    const int n_nodes = in_sizes[0] / NF;   // 50000
    const int n_edges = in_sizes[1];        // 600000
    const int nb = (n_nodes + 255) / 256;

    // ws: rowptr | cnt | edge_src | partials | W1t | W2t | hn(bf16) | h(f32)
    int* rowptr   = (int*)d_ws;
    int* cnt      = rowptr + (n_nodes + 4);
    int* edge_src = cnt + n_nodes;
    int* partials = edge_src + n_edges;
    size_t iw = (size_t)(n_nodes + 4) + n_nodes + n_edges + nb;
    iw = (iw + 63) & ~(size_t)63;  // 256B align
    ushort* W1t = (ushort*)((int*)d_ws + iw);
    ushort* W2t = W1t + 128 * NF;
    ushort* hn  = W2t + 64 * NF;
    float*  h   = (float*)(hn + (size_t)n_nodes * NF);

    hipMemsetAsync(cnt, 0, (size_t)n_nodes * sizeof(int), stream);

    int eb = (n_edges + 255) / 256;
    hist_kernel<<<eb, 256, 0, stream>>>(dst, cnt, n_edges);
    reduce_kernel<<<nb, 256, 0, stream>>>(cnt, partials, n_nodes);
    scan_partials_kernel<<<1, 256, 0, stream>>>(partials, nb);
    scan_apply_kernel<<<nb, 256, 0, stream>>>(cnt, rowptr, partials, n_nodes);
    fill_kernel<<<eb, 256, 0, stream>>>(src, dst, cnt, edge_src, n_edges);
    prep_w_kernel<<<64, 256, 0, stream>>>(W1, W2, W1t, W2t);

    int ab = (n_nodes + 7) / 8;
    int gb = (n_nodes + 63) / 64;

    aggregate_kernel<<<ab, 256, 0, stream>>>(x, rowptr, edge_src, hn, n_nodes);
    gemm_mfma_kernel<128, true><<<gb, 256, 0, stream>>>(hn, W1t, b1, h, n_nodes);
    aggregate_kernel<<<ab, 256, 0, stream>>>(h, rowptr, edge_src, hn, n_nodes);
    gemm_mfma_kernel<64, false><<<gb, 256, 0, stream>>>(hn, W2t, b2, out, n_nodes);
}

// Round 6
// 162.459 us; speedup vs baseline: 13.3104x; 1.1804x over previous
//
#include <hip/hip_runtime.h>

#define NF 128

typedef __attribute__((ext_vector_type(8))) short short8;
typedef __attribute__((ext_vector_type(4))) float f32x4;

__device__ inline ushort f2bf(float f) {
    uint u = __float_as_uint(f);
    return (ushort)((u + 0x7FFFu + ((u >> 16) & 1u)) >> 16);  // RNE
}
__device__ inline float bf2f(ushort u) {
    return __uint_as_float(((uint)u) << 16);
}

// ---------------------------------------------------------------------------
// cnt[dst[e]] += 1
__global__ void hist_kernel(const int* __restrict__ dst, int* __restrict__ cnt,
                            int n_edges) {
    int i = blockIdx.x * blockDim.x + threadIdx.x;
    if (i < n_edges) atomicAdd(&cnt[dst[i]], 1);
}

// ---------------------------------------------------------------------------
__global__ __launch_bounds__(256) void reduce_kernel(const int* __restrict__ cnt,
                                                     int* __restrict__ partials,
                                                     int n) {
    __shared__ int s[256];
    int t = threadIdx.x;
    int i = blockIdx.x * 256 + t;
    s[t] = (i < n) ? cnt[i] : 0;
    __syncthreads();
    for (int off = 128; off > 0; off >>= 1) {
        if (t < off) s[t] += s[t + off];
        __syncthreads();
    }
    if (t == 0) partials[blockIdx.x] = s[0];
}

// ---------------------------------------------------------------------------
__global__ __launch_bounds__(256) void scan_partials_kernel(int* __restrict__ partials,
                                                            int nb) {
    __shared__ int s[256];
    int t = threadIdx.x;
    int carry = 0;
    for (int base = 0; base < nb; base += 256) {
        int v = (base + t < nb) ? partials[base + t] : 0;
        s[t] = v;
        __syncthreads();
        for (int off = 1; off < 256; off <<= 1) {
            int a = (t >= off) ? s[t - off] : 0;
            __syncthreads();
            s[t] += a;
            __syncthreads();
        }
        if (base + t < nb) partials[base + t] = carry + s[t] - v;  // exclusive
        int total = s[255];
        __syncthreads();
        carry += total;
    }
}

// ---------------------------------------------------------------------------
__global__ __launch_bounds__(256) void scan_apply_kernel(int* __restrict__ cnt,
                                                         int* __restrict__ rowptr,
                                                         const int* __restrict__ partials,
                                                         int n) {
    __shared__ int s[256];
    int t = threadIdx.x;
    int i = blockIdx.x * 256 + t;
    int v = (i < n) ? cnt[i] : 0;
    s[t] = v;
    __syncthreads();
    for (int off = 1; off < 256; off <<= 1) {
        int a = (t >= off) ? s[t - off] : 0;
        __syncthreads();
        s[t] += a;
        __syncthreads();
    }
    int off0 = partials[blockIdx.x];
    if (i < n) {
        rowptr[i + 1] = off0 + s[t];
        cnt[i] = off0 + s[t] - v;
    }
    if (blockIdx.x == 0 && t == 0) rowptr[0] = 0;
}

// ---------------------------------------------------------------------------
__global__ void fill_kernel(const int* __restrict__ src,
                            const int* __restrict__ dst,
                            int* __restrict__ cursor,
                            int* __restrict__ edge_src, int n_edges) {
    int i = blockIdx.x * blockDim.x + threadIdx.x;
    if (i < n_edges) {
        int slot = atomicAdd(&cursor[dst[i]], 1);
        edge_src[slot] = src[i];
    }
}

// ---------------------------------------------------------------------------
// W1t[n][k] = bf16(W1[k][n]); W2t[n][k] = bf16(W2[k][n])
__global__ __launch_bounds__(256) void prep_w_kernel(const float* __restrict__ W1,
                                                     const float* __restrict__ W2,
                                                     ushort* __restrict__ W1t,
                                                     ushort* __restrict__ W2t) {
    int t = blockIdx.x * 256 + threadIdx.x;
    if (t < 128 * 128) {
        int k = t >> 7, n = t & 127;
        W1t[n * NF + k] = f2bf(W1[t]);
    }
    if (t < 64 * 128) {
        int k = t >> 6, n = t & 63;
        W2t[n * NF + k] = f2bf(W2[k * 64 + n]);
    }
}

// ---------------------------------------------------------------------------
// out[i] = bf16(in[i]), 8 floats / thread
__global__ __launch_bounds__(256) void f2bf_kernel(const float* __restrict__ in,
                                                   ushort* __restrict__ out, int n8) {
    int i = blockIdx.x * 256 + threadIdx.x;
    if (i >= n8) return;
    const float4* in4 = reinterpret_cast<const float4*>(in);
    float4 v0 = in4[i * 2], v1 = in4[i * 2 + 1];
    short8 o;
    o[0] = (short)f2bf(v0.x); o[1] = (short)f2bf(v0.y);
    o[2] = (short)f2bf(v0.z); o[3] = (short)f2bf(v0.w);
    o[4] = (short)f2bf(v1.x); o[5] = (short)f2bf(v1.y);
    o[6] = (short)f2bf(v1.z); o[7] = (short)f2bf(v1.w);
    *reinterpret_cast<short8*>(&out[i * 8]) = o;
}

// ---------------------------------------------------------------------------
// hn[i] = bf16( (sum_nbrs hb[j] + hb[i]) / (deg+1) ).  bf16 in/out.
// 32 lanes/node, ushort4 (8B) per lane; fp32 accumulate; x4 unroll.
__global__ __launch_bounds__(256) void aggregate_kernel(
    const ushort* __restrict__ hb, const int* __restrict__ rowptr,
    const int* __restrict__ edge_src, ushort* __restrict__ hn, int n_nodes) {
    int t = threadIdx.x;
    int g = t & 31;
    int node = blockIdx.x * 8 + (t >> 5);
    if (node >= n_nodes) return;
    const ushort4* h4 = reinterpret_cast<const ushort4*>(hb);
    int e0 = rowptr[node], e1 = rowptr[node + 1];
    ushort4 sv = h4[(size_t)node * 32 + g];  // self term
    float a0x = bf2f(sv.x), a0y = bf2f(sv.y), a0z = bf2f(sv.z), a0w = bf2f(sv.w);
    float a1x = 0.f, a1y = 0.f, a1z = 0.f, a1w = 0.f;
    float a2x = 0.f, a2y = 0.f, a2z = 0.f, a2w = 0.f;
    float a3x = 0.f, a3y = 0.f, a3z = 0.f, a3w = 0.f;
    for (int base = e0; base < e1; base += 32) {
        int m = min(32, e1 - base);
        int sg = (base + g < e1) ? edge_src[base + g] : 0;
        int j = 0;
        for (; j + 4 <= m; j += 4) {
            int s0 = __shfl(sg, j, 32);
            int s1 = __shfl(sg, j + 1, 32);
            int s2 = __shfl(sg, j + 2, 32);
            int s3 = __shfl(sg, j + 3, 32);
            ushort4 v0 = h4[(size_t)s0 * 32 + g];
            ushort4 v1 = h4[(size_t)s1 * 32 + g];
            ushort4 v2 = h4[(size_t)s2 * 32 + g];
            ushort4 v3 = h4[(size_t)s3 * 32 + g];
            a0x += bf2f(v0.x); a0y += bf2f(v0.y); a0z += bf2f(v0.z); a0w += bf2f(v0.w);
            a1x += bf2f(v1.x); a1y += bf2f(v1.y); a1z += bf2f(v1.z); a1w += bf2f(v1.w);
            a2x += bf2f(v2.x); a2y += bf2f(v2.y); a2z += bf2f(v2.z); a2w += bf2f(v2.w);
            a3x += bf2f(v3.x); a3y += bf2f(v3.y); a3z += bf2f(v3.z); a3w += bf2f(v3.w);
        }
        for (; j < m; ++j) {
            int s = __shfl(sg, j, 32);
            ushort4 v = h4[(size_t)s * 32 + g];
            a0x += bf2f(v.x); a0y += bf2f(v.y); a0z += bf2f(v.z); a0w += bf2f(v.w);
        }
    }
    float inv = 1.0f / (float)(e1 - e0 + 1);
    ushort4 o;
    o.x = f2bf((a0x + a1x + a2x + a3x) * inv);
    o.y = f2bf((a0y + a1y + a2y + a3y) * inv);
    o.z = f2bf((a0z + a1z + a2z + a3z) * inv);
    o.w = f2bf((a0w + a1w + a2w + a3w) * inv);
    reinterpret_cast<ushort4*>(hn)[(size_t)node * 32 + g] = o;
}

// ---------------------------------------------------------------------------
// out = act( A_bf16 @ W + b ), via mfma_f32_16x16x32_bf16.
// A: [n][128] bf16. Wt: [OUTW][128] bf16 (n-major).  256 thr = 4 waves,
// BM=64.  Frag: m/n = lane&15, k = 8*(lane>>4)+i.  C/D: col=lane&15,
// row = 4*(lane>>4)+reg.  BF16OUT selects ushort vs float output.
template <int OUTW, bool RELU, bool BF16OUT>
__global__ __launch_bounds__(256) void gemm_mfma_kernel(
    const ushort* __restrict__ A, const ushort* __restrict__ Wt,
    const float* __restrict__ bias, void* __restrict__ out_v, int n_nodes) {
    constexpr int NT = OUTW / 16;
    __shared__ ushort As[64][136];
    __shared__ ushort Ws[OUTW][136];

    int t = threadIdx.x;
    int row0 = blockIdx.x * 64;
    for (int i = t; i < 64 * 16; i += 256) {       // stage A (bf16x8)
        int r = i >> 4, c = i & 15;
        int gr = row0 + r;
        short8 v = {};
        if (gr < n_nodes)
            v = *reinterpret_cast<const short8*>(&A[(size_t)gr * NF + c * 8]);
        *reinterpret_cast<short8*>(&As[r][c * 8]) = v;
    }
    for (int i = t; i < OUTW * 16; i += 256) {     // stage Wt
        int r = i >> 4, c = i & 15;
        *reinterpret_cast<short8*>(&Ws[r][c * 8]) =
            *reinterpret_cast<const short8*>(&Wt[r * NF + c * 8]);
    }
    __syncthreads();

    int w = t >> 6;
    int l = t & 63;
    int m16 = l & 15;
    int g = l >> 4;
    int m0 = w * 16;

    f32x4 acc[NT];
#pragma unroll
    for (int nt = 0; nt < NT; nt++) acc[nt] = {0.f, 0.f, 0.f, 0.f};

#pragma unroll
    for (int kk = 0; kk < 4; kk++) {
        int k0 = kk * 32 + g * 8;
        short8 a = *reinterpret_cast<const short8*>(&As[m0 + m16][k0]);
#pragma unroll
        for (int nt = 0; nt < NT; nt++) {
            short8 b = *reinterpret_cast<const short8*>(&Ws[nt * 16 + m16][k0]);
            acc[nt] = __builtin_amdgcn_mfma_f32_16x16x32_bf16(a, b, acc[nt], 0, 0, 0);
        }
    }

#pragma unroll
    for (int nt = 0; nt < NT; nt++) {
        int col = nt * 16 + m16;
        float bv = bias[col];
#pragma unroll
        for (int i = 0; i < 4; i++) {
            int gr = row0 + m0 + g * 4 + i;
            if (gr < n_nodes) {
                float v = acc[nt][i] + bv;
                if (RELU) v = fmaxf(v, 0.f);
                if (BF16OUT)
                    ((ushort*)out_v)[(size_t)gr * OUTW + col] = f2bf(v);
                else
                    ((float*)out_v)[(size_t)gr * OUTW + col] = v;
            }
        }
    }
}

// ---------------------------------------------------------------------------
extern "C" void kernel_launch(void* const* d_in, const int* in_sizes, int n_in,
                              void* d_out, int out_size, void* d_ws, size_t ws_size,
                              hipStream_t stream) {
    const float* x   = (const float*)d_in[0];
    const int*   src = (const int*)d_in[1];
    const int*   dst = (const int*)d_in[2];
    const float* W1  = (const float*)d_in[3];
    const float* b1  = (const float*)d_in[4];
    const float* W2  = (const float*)d_in[5];
    const float* b2  = (const float*)d_in[6];
    float* out = (float*)d_out;

    const int n_nodes = in_sizes[0] / NF;   // 50000
    const int n_edges = in_sizes[1];        // 600000
    const int nb = (n_nodes + 255) / 256;

    // ws: rowptr | cnt | edge_src | partials | W1t | W2t | xb | hn | hbuf
    int* rowptr   = (int*)d_ws;
    int* cnt      = rowptr + (n_nodes + 4);
    int* edge_src = cnt + n_nodes;
    int* partials = edge_src + n_edges;
    size_t iw = (size_t)(n_nodes + 4) + n_nodes + n_edges + nb;
    iw = (iw + 63) & ~(size_t)63;  // 256B align
    ushort* W1t = (ushort*)((int*)d_ws + iw);
    ushort* W2t = W1t + 128 * NF;
    ushort* xb  = W2t + 64 * NF;
    ushort* hn  = xb + (size_t)n_nodes * NF;
    ushort* hbuf = hn + (size_t)n_nodes * NF;

    hipMemsetAsync(cnt, 0, (size_t)n_nodes * sizeof(int), stream);

    int eb = (n_edges + 255) / 256;
    hist_kernel<<<eb, 256, 0, stream>>>(dst, cnt, n_edges);
    reduce_kernel<<<nb, 256, 0, stream>>>(cnt, partials, n_nodes);
    scan_partials_kernel<<<1, 256, 0, stream>>>(partials, nb);
    scan_apply_kernel<<<nb, 256, 0, stream>>>(cnt, rowptr, partials, n_nodes);
    fill_kernel<<<eb, 256, 0, stream>>>(src, dst, cnt, edge_src, n_edges);
    prep_w_kernel<<<64, 256, 0, stream>>>(W1, W2, W1t, W2t);

    int n8 = n_nodes * NF / 8;
    f2bf_kernel<<<(n8 + 255) / 256, 256, 0, stream>>>(x, xb, n8);

    int ab = (n_nodes + 7) / 8;
    int gb = (n_nodes + 63) / 64;

    aggregate_kernel<<<ab, 256, 0, stream>>>(xb, rowptr, edge_src, hn, n_nodes);
    gemm_mfma_kernel<128, true, true><<<gb, 256, 0, stream>>>(hn, W1t, b1, hbuf, n_nodes);
    aggregate_kernel<<<ab, 256, 0, stream>>>(hbuf, rowptr, edge_src, hn, n_nodes);
    gemm_mfma_kernel<64, false, false><<<gb, 256, 0, stream>>>(hn, W2t, b2, out, n_nodes);
}

// Round 7
// 157.991 us; speedup vs baseline: 13.6868x; 1.0283x over previous
//
#include <hip/hip_runtime.h>

#define NF 128

typedef __attribute__((ext_vector_type(8))) short short8;
typedef __attribute__((ext_vector_type(4))) float f32x4;

__device__ inline ushort f2bf(float f) {
    uint u = __float_as_uint(f);
    return (ushort)((u + 0x7FFFu + ((u >> 16) & 1u)) >> 16);  // RNE
}
__device__ inline float bf2f(ushort u) {
    return __uint_as_float(((uint)u) << 16);
}

// ---------------------------------------------------------------------------
// zero n4 int4's (grid-stride)
__global__ __launch_bounds__(256) void zero_kernel(int4* __restrict__ p, int n4) {
    int i = blockIdx.x * 256 + threadIdx.x;
    int stride = gridDim.x * 256;
    int4 z = make_int4(0, 0, 0, 0);
    for (; i < n4; i += stride) p[i] = z;
}

// ---------------------------------------------------------------------------
// cnt[dst[e]] += 1
__global__ void hist_kernel(const int* __restrict__ dst, int* __restrict__ cnt,
                            int n_edges) {
    int i = blockIdx.x * blockDim.x + threadIdx.x;
    if (i < n_edges) atomicAdd(&cnt[dst[i]], 1);
}

// ---------------------------------------------------------------------------
__global__ __launch_bounds__(256) void reduce_kernel(const int* __restrict__ cnt,
                                                     int* __restrict__ partials,
                                                     int n) {
    __shared__ int s[256];
    int t = threadIdx.x;
    int i = blockIdx.x * 256 + t;
    s[t] = (i < n) ? cnt[i] : 0;
    __syncthreads();
    for (int off = 128; off > 0; off >>= 1) {
        if (t < off) s[t] += s[t + off];
        __syncthreads();
    }
    if (t == 0) partials[blockIdx.x] = s[0];
}

// ---------------------------------------------------------------------------
__global__ __launch_bounds__(256) void scan_partials_kernel(int* __restrict__ partials,
                                                            int nb) {
    __shared__ int s[256];
    int t = threadIdx.x;
    int carry = 0;
    for (int base = 0; base < nb; base += 256) {
        int v = (base + t < nb) ? partials[base + t] : 0;
        s[t] = v;
        __syncthreads();
        for (int off = 1; off < 256; off <<= 1) {
            int a = (t >= off) ? s[t - off] : 0;
            __syncthreads();
            s[t] += a;
            __syncthreads();
        }
        if (base + t < nb) partials[base + t] = carry + s[t] - v;  // exclusive
        int total = s[255];
        __syncthreads();
        carry += total;
    }
}

// ---------------------------------------------------------------------------
__global__ __launch_bounds__(256) void scan_apply_kernel(int* __restrict__ cnt,
                                                         int* __restrict__ rowptr,
                                                         const int* __restrict__ partials,
                                                         int n) {
    __shared__ int s[256];
    int t = threadIdx.x;
    int i = blockIdx.x * 256 + t;
    int v = (i < n) ? cnt[i] : 0;
    s[t] = v;
    __syncthreads();
    for (int off = 1; off < 256; off <<= 1) {
        int a = (t >= off) ? s[t - off] : 0;
        __syncthreads();
        s[t] += a;
        __syncthreads();
    }
    int off0 = partials[blockIdx.x];
    if (i < n) {
        rowptr[i + 1] = off0 + s[t];
        cnt[i] = off0 + s[t] - v;
    }
    if (blockIdx.x == 0 && t == 0) rowptr[0] = 0;
}

// ---------------------------------------------------------------------------
__global__ void fill_kernel(const int* __restrict__ src,
                            const int* __restrict__ dst,
                            int* __restrict__ cursor,
                            int* __restrict__ edge_src, int n_edges) {
    int i = blockIdx.x * blockDim.x + threadIdx.x;
    if (i < n_edges) {
        int slot = atomicAdd(&cursor[dst[i]], 1);
        edge_src[slot] = src[i];
    }
}

// ---------------------------------------------------------------------------
// W1t[n][k] = bf16(W1[k][n]); W2t[n][k] = bf16(W2[k][n])
__global__ __launch_bounds__(256) void prep_w_kernel(const float* __restrict__ W1,
                                                     const float* __restrict__ W2,
                                                     ushort* __restrict__ W1t,
                                                     ushort* __restrict__ W2t) {
    int t = blockIdx.x * 256 + threadIdx.x;
    if (t < 128 * 128) {
        int k = t >> 7, n = t & 127;
        W1t[n * NF + k] = f2bf(W1[t]);
    }
    if (t < 64 * 128) {
        int k = t >> 6, n = t & 63;
        W2t[n * NF + k] = f2bf(W2[k * 64 + n]);
    }
}

// ---------------------------------------------------------------------------
// out[i] = bf16(in[i]), 8 floats / thread
__global__ __launch_bounds__(256) void f2bf_kernel(const float* __restrict__ in,
                                                   ushort* __restrict__ out, int n8) {
    int i = blockIdx.x * 256 + threadIdx.x;
    if (i >= n8) return;
    const float4* in4 = reinterpret_cast<const float4*>(in);
    float4 v0 = in4[i * 2], v1 = in4[i * 2 + 1];
    short8 o;
    o[0] = (short)f2bf(v0.x); o[1] = (short)f2bf(v0.y);
    o[2] = (short)f2bf(v0.z); o[3] = (short)f2bf(v0.w);
    o[4] = (short)f2bf(v1.x); o[5] = (short)f2bf(v1.y);
    o[6] = (short)f2bf(v1.z); o[7] = (short)f2bf(v1.w);
    *reinterpret_cast<short8*>(&out[i * 8]) = o;
}

// ---------------------------------------------------------------------------
// hn[i] = bf16( (sum_nbrs hb[j] + hb[i]) / (deg+1) ).  bf16 in/out.
// 32 lanes/node, ushort4 (8B) per lane; fp32 accumulate; x4 unroll.
__global__ __launch_bounds__(256) void aggregate_kernel(
    const ushort* __restrict__ hb, const int* __restrict__ rowptr,
    const int* __restrict__ edge_src, ushort* __restrict__ hn, int n_nodes) {
    int t = threadIdx.x;
    int g = t & 31;
    int node = blockIdx.x * 8 + (t >> 5);
    if (node >= n_nodes) return;
    const ushort4* h4 = reinterpret_cast<const ushort4*>(hb);
    int e0 = rowptr[node], e1 = rowptr[node + 1];
    ushort4 sv = h4[(size_t)node * 32 + g];  // self term
    float a0x = bf2f(sv.x), a0y = bf2f(sv.y), a0z = bf2f(sv.z), a0w = bf2f(sv.w);
    float a1x = 0.f, a1y = 0.f, a1z = 0.f, a1w = 0.f;
    float a2x = 0.f, a2y = 0.f, a2z = 0.f, a2w = 0.f;
    float a3x = 0.f, a3y = 0.f, a3z = 0.f, a3w = 0.f;
    for (int base = e0; base < e1; base += 32) {
        int m = min(32, e1 - base);
        int sg = (base + g < e1) ? edge_src[base + g] : 0;
        int j = 0;
        for (; j + 4 <= m; j += 4) {
            int s0 = __shfl(sg, j, 32);
            int s1 = __shfl(sg, j + 1, 32);
            int s2 = __shfl(sg, j + 2, 32);
            int s3 = __shfl(sg, j + 3, 32);
            ushort4 v0 = h4[(size_t)s0 * 32 + g];
            ushort4 v1 = h4[(size_t)s1 * 32 + g];
            ushort4 v2 = h4[(size_t)s2 * 32 + g];
            ushort4 v3 = h4[(size_t)s3 * 32 + g];
            a0x += bf2f(v0.x); a0y += bf2f(v0.y); a0z += bf2f(v0.z); a0w += bf2f(v0.w);
            a1x += bf2f(v1.x); a1y += bf2f(v1.y); a1z += bf2f(v1.z); a1w += bf2f(v1.w);
            a2x += bf2f(v2.x); a2y += bf2f(v2.y); a2z += bf2f(v2.z); a2w += bf2f(v2.w);
            a3x += bf2f(v3.x); a3y += bf2f(v3.y); a3z += bf2f(v3.z); a3w += bf2f(v3.w);
        }
        for (; j < m; ++j) {
            int s = __shfl(sg, j, 32);
            ushort4 v = h4[(size_t)s * 32 + g];
            a0x += bf2f(v.x); a0y += bf2f(v.y); a0z += bf2f(v.z); a0w += bf2f(v.w);
        }
    }
    float inv = 1.0f / (float)(e1 - e0 + 1);
    ushort4 o;
    o.x = f2bf((a0x + a1x + a2x + a3x) * inv);
    o.y = f2bf((a0y + a1y + a2y + a3y) * inv);
    o.z = f2bf((a0z + a1z + a2z + a3z) * inv);
    o.w = f2bf((a0w + a1w + a2w + a3w) * inv);
    reinterpret_cast<ushort4*>(hn)[(size_t)node * 32 + g] = o;
}

// ---------------------------------------------------------------------------
// out = act( A_bf16 @ W + b ), via mfma_f32_16x16x32_bf16.
// A: [n][128] bf16. Wt: [OUTW][128] bf16 (n-major).  256 thr = 4 waves,
// BM=64.  Frag: m/n = lane&15, k = 8*(lane>>4)+i.  C/D: col=lane&15,
// row = 4*(lane>>4)+reg.  BF16OUT selects ushort vs float output.
template <int OUTW, bool RELU, bool BF16OUT>
__global__ __launch_bounds__(256) void gemm_mfma_kernel(
    const ushort* __restrict__ A, const ushort* __restrict__ Wt,
    const float* __restrict__ bias, void* __restrict__ out_v, int n_nodes) {
    constexpr int NT = OUTW / 16;
    __shared__ ushort As[64][136];
    __shared__ ushort Ws[OUTW][136];

    int t = threadIdx.x;
    int row0 = blockIdx.x * 64;
    for (int i = t; i < 64 * 16; i += 256) {       // stage A (bf16x8)
        int r = i >> 4, c = i & 15;
        int gr = row0 + r;
        short8 v = {};
        if (gr < n_nodes)
            v = *reinterpret_cast<const short8*>(&A[(size_t)gr * NF + c * 8]);
        *reinterpret_cast<short8*>(&As[r][c * 8]) = v;
    }
    for (int i = t; i < OUTW * 16; i += 256) {     // stage Wt
        int r = i >> 4, c = i & 15;
        *reinterpret_cast<short8*>(&Ws[r][c * 8]) =
            *reinterpret_cast<const short8*>(&Wt[r * NF + c * 8]);
    }
    __syncthreads();

    int w = t >> 6;
    int l = t & 63;
    int m16 = l & 15;
    int g = l >> 4;
    int m0 = w * 16;

    f32x4 acc[NT];
#pragma unroll
    for (int nt = 0; nt < NT; nt++) acc[nt] = {0.f, 0.f, 0.f, 0.f};

#pragma unroll
    for (int kk = 0; kk < 4; kk++) {
        int k0 = kk * 32 + g * 8;
        short8 a = *reinterpret_cast<const short8*>(&As[m0 + m16][k0]);
#pragma unroll
        for (int nt = 0; nt < NT; nt++) {
            short8 b = *reinterpret_cast<const short8*>(&Ws[nt * 16 + m16][k0]);
            acc[nt] = __builtin_amdgcn_mfma_f32_16x16x32_bf16(a, b, acc[nt], 0, 0, 0);
        }
    }

#pragma unroll
    for (int nt = 0; nt < NT; nt++) {
        int col = nt * 16 + m16;
        float bv = bias[col];
#pragma unroll
        for (int i = 0; i < 4; i++) {
            int gr = row0 + m0 + g * 4 + i;
            if (gr < n_nodes) {
                float v = acc[nt][i] + bv;
                if (RELU) v = fmaxf(v, 0.f);
                if (BF16OUT)
                    ((ushort*)out_v)[(size_t)gr * OUTW + col] = f2bf(v);
                else
                    ((float*)out_v)[(size_t)gr * OUTW + col] = v;
            }
        }
    }
}

// ---------------------------------------------------------------------------
extern "C" void kernel_launch(void* const* d_in, const int* in_sizes, int n_in,
                              void* d_out, int out_size, void* d_ws, size_t ws_size,
                              hipStream_t stream) {
    const float* x   = (const float*)d_in[0];
    const int*   src = (const int*)d_in[1];
    const int*   dst = (const int*)d_in[2];
    const float* W1  = (const float*)d_in[3];
    const float* b1  = (const float*)d_in[4];
    const float* W2  = (const float*)d_in[5];
    const float* b2  = (const float*)d_in[6];
    float* out = (float*)d_out;

    const int n_nodes = in_sizes[0] / NF;   // 50000
    const int n_edges = in_sizes[1];        // 600000
    const int nb = (n_nodes + 255) / 256;

    // ws: rowptr | cnt | edge_src | partials | W1t | W2t | xb | hn | hbuf
    int* rowptr   = (int*)d_ws;
    int* cnt      = rowptr + (n_nodes + 4);
    int* edge_src = cnt + n_nodes;
    int* partials = edge_src + n_edges;
    size_t iw = (size_t)(n_nodes + 4) + n_nodes + n_edges + nb;
    iw = (iw + 63) & ~(size_t)63;  // 256B align
    ushort* W1t = (ushort*)((int*)d_ws + iw);
    ushort* W2t = W1t + 128 * NF;
    ushort* xb  = W2t + 64 * NF;
    ushort* hn  = xb + (size_t)n_nodes * NF;
    ushort* hbuf = hn + (size_t)n_nodes * NF;

    // zero cnt (n_nodes ints; n_nodes % 4 == 0)
    zero_kernel<<<50, 256, 0, stream>>>((int4*)cnt, n_nodes / 4);

    int eb = (n_edges + 255) / 256;
    hist_kernel<<<eb, 256, 0, stream>>>(dst, cnt, n_edges);
    reduce_kernel<<<nb, 256, 0, stream>>>(cnt, partials, n_nodes);
    scan_partials_kernel<<<1, 256, 0, stream>>>(partials, nb);
    scan_apply_kernel<<<nb, 256, 0, stream>>>(cnt, rowptr, partials, n_nodes);
    fill_kernel<<<eb, 256, 0, stream>>>(src, dst, cnt, edge_src, n_edges);
    prep_w_kernel<<<64, 256, 0, stream>>>(W1, W2, W1t, W2t);

    int n8 = n_nodes * NF / 8;
    f2bf_kernel<<<(n8 + 255) / 256, 256, 0, stream>>>(x, xb, n8);

    int ab = (n_nodes + 7) / 8;
    int gb = (n_nodes + 63) / 64;

    aggregate_kernel<<<ab, 256, 0, stream>>>(xb, rowptr, edge_src, hn, n_nodes);
    gemm_mfma_kernel<128, true, true><<<gb, 256, 0, stream>>>(hn, W1t, b1, hbuf, n_nodes);
    aggregate_kernel<<<ab, 256, 0, stream>>>(hbuf, rowptr, edge_src, hn, n_nodes);
    gemm_mfma_kernel<64, false, false><<<gb, 256, 0, stream>>>(hn, W2t, b2, out, n_nodes);
}

// Round 8
// 151.933 us; speedup vs baseline: 14.2325x; 1.0399x over previous
//
#include <hip/hip_runtime.h>

#define NF 128

typedef __attribute__((ext_vector_type(8))) short short8;
typedef __attribute__((ext_vector_type(4))) float f32x4;

__device__ inline ushort f2bf(float f) {
    uint u = __float_as_uint(f);
    return (ushort)((u + 0x7FFFu + ((u >> 16) & 1u)) >> 16);  // RNE
}
__device__ inline float bf2f(ushort u) {
    return __uint_as_float(((uint)u) << 16);
}

// ---------------------------------------------------------------------------
// zero n4 int4's (grid-stride)
__global__ __launch_bounds__(256) void zero_kernel(int4* __restrict__ p, int n4) {
    int i = blockIdx.x * 256 + threadIdx.x;
    int stride = gridDim.x * 256;
    int4 z = make_int4(0, 0, 0, 0);
    for (; i < n4; i += stride) p[i] = z;
}

// ---------------------------------------------------------------------------
// cnt[dst[e]] += 1
__global__ void hist_kernel(const int* __restrict__ dst, int* __restrict__ cnt,
                            int n_edges) {
    int i = blockIdx.x * blockDim.x + threadIdx.x;
    if (i < n_edges) atomicAdd(&cnt[dst[i]], 1);
}

// ---------------------------------------------------------------------------
__global__ __launch_bounds__(256) void reduce_kernel(const int* __restrict__ cnt,
                                                     int* __restrict__ partials,
                                                     int n) {
    __shared__ int s[256];
    int t = threadIdx.x;
    int i = blockIdx.x * 256 + t;
    s[t] = (i < n) ? cnt[i] : 0;
    __syncthreads();
    for (int off = 128; off > 0; off >>= 1) {
        if (t < off) s[t] += s[t + off];
        __syncthreads();
    }
    if (t == 0) partials[blockIdx.x] = s[0];
}

// ---------------------------------------------------------------------------
__global__ __launch_bounds__(256) void scan_partials_kernel(int* __restrict__ partials,
                                                            int nb) {
    __shared__ int s[256];
    int t = threadIdx.x;
    int carry = 0;
    for (int base = 0; base < nb; base += 256) {
        int v = (base + t < nb) ? partials[base + t] : 0;
        s[t] = v;
        __syncthreads();
        for (int off = 1; off < 256; off <<= 1) {
            int a = (t >= off) ? s[t - off] : 0;
            __syncthreads();
            s[t] += a;
            __syncthreads();
        }
        if (base + t < nb) partials[base + t] = carry + s[t] - v;  // exclusive
        int total = s[255];
        __syncthreads();
        carry += total;
    }
}

// ---------------------------------------------------------------------------
__global__ __launch_bounds__(256) void scan_apply_kernel(int* __restrict__ cnt,
                                                         int* __restrict__ rowptr,
                                                         const int* __restrict__ partials,
                                                         int n) {
    __shared__ int s[256];
    int t = threadIdx.x;
    int i = blockIdx.x * 256 + t;
    int v = (i < n) ? cnt[i] : 0;
    s[t] = v;
    __syncthreads();
    for (int off = 1; off < 256; off <<= 1) {
        int a = (t >= off) ? s[t - off] : 0;
        __syncthreads();
        s[t] += a;
        __syncthreads();
    }
    int off0 = partials[blockIdx.x];
    if (i < n) {
        rowptr[i + 1] = off0 + s[t];
        cnt[i] = off0 + s[t] - v;
    }
    if (blockIdx.x == 0 && t == 0) rowptr[0] = 0;
}

// ---------------------------------------------------------------------------
__global__ void fill_kernel(const int* __restrict__ src,
                            const int* __restrict__ dst,
                            int* __restrict__ cursor,
                            int* __restrict__ edge_src, int n_edges) {
    int i = blockIdx.x * blockDim.x + threadIdx.x;
    if (i < n_edges) {
        int slot = atomicAdd(&cursor[dst[i]], 1);
        edge_src[slot] = src[i];
    }
}

// ---------------------------------------------------------------------------
// Fused prep: blocks [0,64) convert W1/W2 -> transposed bf16;
// blocks [64,...) convert x -> bf16 (8 floats/thread).
__global__ __launch_bounds__(256) void prep_kernel(
    const float* __restrict__ x, const float* __restrict__ W1,
    const float* __restrict__ W2, ushort* __restrict__ xb,
    ushort* __restrict__ W1t, ushort* __restrict__ W2t, int n8) {
    int b = blockIdx.x;
    if (b < 64) {
        int t = b * 256 + threadIdx.x;
        if (t < 128 * 128) {
            int k = t >> 7, n = t & 127;
            W1t[n * NF + k] = f2bf(W1[t]);
        }
        if (t < 64 * 128) {
            int k = t >> 6, n = t & 63;
            W2t[n * NF + k] = f2bf(W2[k * 64 + n]);
        }
    } else {
        int i = (b - 64) * 256 + threadIdx.x;
        if (i >= n8) return;
        const float4* in4 = reinterpret_cast<const float4*>(x);
        float4 v0 = in4[i * 2], v1 = in4[i * 2 + 1];
        short8 o;
        o[0] = (short)f2bf(v0.x); o[1] = (short)f2bf(v0.y);
        o[2] = (short)f2bf(v0.z); o[3] = (short)f2bf(v0.w);
        o[4] = (short)f2bf(v1.x); o[5] = (short)f2bf(v1.y);
        o[6] = (short)f2bf(v1.z); o[7] = (short)f2bf(v1.w);
        *reinterpret_cast<short8*>(&xb[i * 8]) = o;
    }
}

// ---------------------------------------------------------------------------
// hn[i] = bf16( (sum_nbrs hb[j] + hb[i]) / (deg+1) ).  128-dim bf16 in/out.
// 32 lanes/node, ushort4 (8B) per lane; fp32 accumulate; x4 unroll.
__global__ __launch_bounds__(256) void aggregate_kernel(
    const ushort* __restrict__ hb, const int* __restrict__ rowptr,
    const int* __restrict__ edge_src, ushort* __restrict__ hn, int n_nodes) {
    int t = threadIdx.x;
    int g = t & 31;
    int node = blockIdx.x * 8 + (t >> 5);
    if (node >= n_nodes) return;
    const ushort4* h4 = reinterpret_cast<const ushort4*>(hb);
    int e0 = rowptr[node], e1 = rowptr[node + 1];
    ushort4 sv = h4[(size_t)node * 32 + g];  // self term
    float a0x = bf2f(sv.x), a0y = bf2f(sv.y), a0z = bf2f(sv.z), a0w = bf2f(sv.w);
    float a1x = 0.f, a1y = 0.f, a1z = 0.f, a1w = 0.f;
    float a2x = 0.f, a2y = 0.f, a2z = 0.f, a2w = 0.f;
    float a3x = 0.f, a3y = 0.f, a3z = 0.f, a3w = 0.f;
    for (int base = e0; base < e1; base += 32) {
        int m = min(32, e1 - base);
        int sg = (base + g < e1) ? edge_src[base + g] : 0;
        int j = 0;
        for (; j + 4 <= m; j += 4) {
            int s0 = __shfl(sg, j, 32);
            int s1 = __shfl(sg, j + 1, 32);
            int s2 = __shfl(sg, j + 2, 32);
            int s3 = __shfl(sg, j + 3, 32);
            ushort4 v0 = h4[(size_t)s0 * 32 + g];
            ushort4 v1 = h4[(size_t)s1 * 32 + g];
            ushort4 v2 = h4[(size_t)s2 * 32 + g];
            ushort4 v3 = h4[(size_t)s3 * 32 + g];
            a0x += bf2f(v0.x); a0y += bf2f(v0.y); a0z += bf2f(v0.z); a0w += bf2f(v0.w);
            a1x += bf2f(v1.x); a1y += bf2f(v1.y); a1z += bf2f(v1.z); a1w += bf2f(v1.w);
            a2x += bf2f(v2.x); a2y += bf2f(v2.y); a2z += bf2f(v2.z); a2w += bf2f(v2.w);
            a3x += bf2f(v3.x); a3y += bf2f(v3.y); a3z += bf2f(v3.z); a3w += bf2f(v3.w);
        }
        for (; j < m; ++j) {
            int s = __shfl(sg, j, 32);
            ushort4 v = h4[(size_t)s * 32 + g];
            a0x += bf2f(v.x); a0y += bf2f(v.y); a0z += bf2f(v.z); a0w += bf2f(v.w);
        }
    }
    float inv = 1.0f / (float)(e1 - e0 + 1);
    ushort4 o;
    o.x = f2bf((a0x + a1x + a2x + a3x) * inv);
    o.y = f2bf((a0y + a1y + a2y + a3y) * inv);
    o.z = f2bf((a0z + a1z + a2z + a3z) * inv);
    o.w = f2bf((a0w + a1w + a2w + a3w) * inv);
    reinterpret_cast<ushort4*>(hn)[(size_t)node * 32 + g] = o;
}

// ---------------------------------------------------------------------------
// out[i] = (sum_nbrs y[j] + y[i]) / (deg+1) + b.   64-dim bf16 in, fp32 out.
// 16 lanes/node (ushort4 = 4 feats each), 16 nodes/block.
__global__ __launch_bounds__(256) void aggregate64_kernel(
    const ushort* __restrict__ y, const int* __restrict__ rowptr,
    const int* __restrict__ edge_src, const float* __restrict__ b,
    float* __restrict__ out, int n_nodes) {
    int t = threadIdx.x;
    int g = t & 15;
    int node = blockIdx.x * 16 + (t >> 4);
    if (node >= n_nodes) return;
    const ushort4* y4 = reinterpret_cast<const ushort4*>(y);
    int e0 = rowptr[node], e1 = rowptr[node + 1];
    ushort4 sv = y4[(size_t)node * 16 + g];  // self term
    float a0x = bf2f(sv.x), a0y = bf2f(sv.y), a0z = bf2f(sv.z), a0w = bf2f(sv.w);
    float a1x = 0.f, a1y = 0.f, a1z = 0.f, a1w = 0.f;
    float a2x = 0.f, a2y = 0.f, a2z = 0.f, a2w = 0.f;
    float a3x = 0.f, a3y = 0.f, a3z = 0.f, a3w = 0.f;
    for (int base = e0; base < e1; base += 16) {
        int m = min(16, e1 - base);
        int sg = (base + g < e1) ? edge_src[base + g] : 0;
        int j = 0;
        for (; j + 4 <= m; j += 4) {
            int s0 = __shfl(sg, j, 16);
            int s1 = __shfl(sg, j + 1, 16);
            int s2 = __shfl(sg, j + 2, 16);
            int s3 = __shfl(sg, j + 3, 16);
            ushort4 v0 = y4[(size_t)s0 * 16 + g];
            ushort4 v1 = y4[(size_t)s1 * 16 + g];
            ushort4 v2 = y4[(size_t)s2 * 16 + g];
            ushort4 v3 = y4[(size_t)s3 * 16 + g];
            a0x += bf2f(v0.x); a0y += bf2f(v0.y); a0z += bf2f(v0.z); a0w += bf2f(v0.w);
            a1x += bf2f(v1.x); a1y += bf2f(v1.y); a1z += bf2f(v1.z); a1w += bf2f(v1.w);
            a2x += bf2f(v2.x); a2y += bf2f(v2.y); a2z += bf2f(v2.z); a2w += bf2f(v2.w);
            a3x += bf2f(v3.x); a3y += bf2f(v3.y); a3z += bf2f(v3.z); a3w += bf2f(v3.w);
        }
        for (; j < m; ++j) {
            int s = __shfl(sg, j, 16);
            ushort4 v = y4[(size_t)s * 16 + g];
            a0x += bf2f(v.x); a0y += bf2f(v.y); a0z += bf2f(v.z); a0w += bf2f(v.w);
        }
    }
    float inv = 1.0f / (float)(e1 - e0 + 1);
    float4 bv = reinterpret_cast<const float4*>(b)[g];
    float4 o;
    o.x = (a0x + a1x + a2x + a3x) * inv + bv.x;
    o.y = (a0y + a1y + a2y + a3y) * inv + bv.y;
    o.z = (a0z + a1z + a2z + a3z) * inv + bv.z;
    o.w = (a0w + a1w + a2w + a3w) * inv + bv.w;
    reinterpret_cast<float4*>(out)[(size_t)node * 16 + g] = o;
}

// ---------------------------------------------------------------------------
// out = act( A_bf16 @ W [+ b] ), via mfma_f32_16x16x32_bf16.
// A: [n][128] bf16. Wt: [OUTW][128] bf16 (n-major).  256 thr = 4 waves,
// BM=64.  Frag: m/n = lane&15, k = 8*(lane>>4)+i.  C/D: col=lane&15,
// row = 4*(lane>>4)+reg.
template <int OUTW, bool RELU, bool BF16OUT, bool BIAS>
__global__ __launch_bounds__(256) void gemm_mfma_kernel(
    const ushort* __restrict__ A, const ushort* __restrict__ Wt,
    const float* __restrict__ bias, void* __restrict__ out_v, int n_nodes) {
    constexpr int NT = OUTW / 16;
    __shared__ ushort As[64][136];
    __shared__ ushort Ws[OUTW][136];

    int t = threadIdx.x;
    int row0 = blockIdx.x * 64;
    for (int i = t; i < 64 * 16; i += 256) {       // stage A (bf16x8)
        int r = i >> 4, c = i & 15;
        int gr = row0 + r;
        short8 v = {};
        if (gr < n_nodes)
            v = *reinterpret_cast<const short8*>(&A[(size_t)gr * NF + c * 8]);
        *reinterpret_cast<short8*>(&As[r][c * 8]) = v;
    }
    for (int i = t; i < OUTW * 16; i += 256) {     // stage Wt
        int r = i >> 4, c = i & 15;
        *reinterpret_cast<short8*>(&Ws[r][c * 8]) =
            *reinterpret_cast<const short8*>(&Wt[r * NF + c * 8]);
    }
    __syncthreads();

    int w = t >> 6;
    int l = t & 63;
    int m16 = l & 15;
    int g = l >> 4;
    int m0 = w * 16;

    f32x4 acc[NT];
#pragma unroll
    for (int nt = 0; nt < NT; nt++) acc[nt] = {0.f, 0.f, 0.f, 0.f};

#pragma unroll
    for (int kk = 0; kk < 4; kk++) {
        int k0 = kk * 32 + g * 8;
        short8 a = *reinterpret_cast<const short8*>(&As[m0 + m16][k0]);
#pragma unroll
        for (int nt = 0; nt < NT; nt++) {
            short8 b = *reinterpret_cast<const short8*>(&Ws[nt * 16 + m16][k0]);
            acc[nt] = __builtin_amdgcn_mfma_f32_16x16x32_bf16(a, b, acc[nt], 0, 0, 0);
        }
    }

#pragma unroll
    for (int nt = 0; nt < NT; nt++) {
        int col = nt * 16 + m16;
        float bv = BIAS ? bias[col] : 0.f;
#pragma unroll
        for (int i = 0; i < 4; i++) {
            int gr = row0 + m0 + g * 4 + i;
            if (gr < n_nodes) {
                float v = acc[nt][i] + bv;
                if (RELU) v = fmaxf(v, 0.f);
                if (BF16OUT)
                    ((ushort*)out_v)[(size_t)gr * OUTW + col] = f2bf(v);
                else
                    ((float*)out_v)[(size_t)gr * OUTW + col] = v;
            }
        }
    }
}

// ---------------------------------------------------------------------------
extern "C" void kernel_launch(void* const* d_in, const int* in_sizes, int n_in,
                              void* d_out, int out_size, void* d_ws, size_t ws_size,
                              hipStream_t stream) {
    const float* x   = (const float*)d_in[0];
    const int*   src = (const int*)d_in[1];
    const int*   dst = (const int*)d_in[2];
    const float* W1  = (const float*)d_in[3];
    const float* b1  = (const float*)d_in[4];
    const float* W2  = (const float*)d_in[5];
    const float* b2  = (const float*)d_in[6];
    float* out = (float*)d_out;

    const int n_nodes = in_sizes[0] / NF;   // 50000
    const int n_edges = in_sizes[1];        // 600000
    const int nb = (n_nodes + 255) / 256;

    // ws: rowptr | cnt | edge_src | partials | W1t | W2t | xb | hn | hbuf | y
    int* rowptr   = (int*)d_ws;
    int* cnt      = rowptr + (n_nodes + 4);
    int* edge_src = cnt + n_nodes;
    int* partials = edge_src + n_edges;
    size_t iw = (size_t)(n_nodes + 4) + n_nodes + n_edges + nb;
    iw = (iw + 63) & ~(size_t)63;  // 256B align
    ushort* W1t  = (ushort*)((int*)d_ws + iw);
    ushort* W2t  = W1t + 128 * NF;
    ushort* xb   = W2t + 64 * NF;
    ushort* hn   = xb + (size_t)n_nodes * NF;
    ushort* hbuf = hn + (size_t)n_nodes * NF;
    ushort* y    = hbuf + (size_t)n_nodes * NF;

    zero_kernel<<<50, 256, 0, stream>>>((int4*)cnt, n_nodes / 4);

    int eb = (n_edges + 255) / 256;
    hist_kernel<<<eb, 256, 0, stream>>>(dst, cnt, n_edges);
    reduce_kernel<<<nb, 256, 0, stream>>>(cnt, partials, n_nodes);
    scan_partials_kernel<<<1, 256, 0, stream>>>(partials, nb);
    scan_apply_kernel<<<nb, 256, 0, stream>>>(cnt, rowptr, partials, n_nodes);
    fill_kernel<<<eb, 256, 0, stream>>>(src, dst, cnt, edge_src, n_edges);

    int n8 = n_nodes * NF / 8;
    prep_kernel<<<64 + (n8 + 255) / 256, 256, 0, stream>>>(x, W1, W2, xb, W1t, W2t, n8);

    int ab = (n_nodes + 7) / 8;
    int gb = (n_nodes + 63) / 64;

    aggregate_kernel<<<ab, 256, 0, stream>>>(xb, rowptr, edge_src, hn, n_nodes);
    gemm_mfma_kernel<128, true, true, true><<<gb, 256, 0, stream>>>(hn, W1t, b1, hbuf, n_nodes);
    // push W2 through the (linear) aggregation: y = h @ W2, out = agg(y) + b2
    gemm_mfma_kernel<64, false, true, false><<<gb, 256, 0, stream>>>(hbuf, W2t, nullptr, y, n_nodes);
    aggregate64_kernel<<<(n_nodes + 15) / 16, 256, 0, stream>>>(y, rowptr, edge_src, b2, out, n_nodes);
}